// Round 1
// baseline (416.874 us; speedup 1.0000x reference)
//
#include <hip/hip_runtime.h>

// Simple_Cross2: x[16384,512] -> cross -> 2048 -> 2048 -> 1024 -> 512 -> 1
// Strategy: bf16 MFMA (16x16x32) GEMMs with fp32 accumulation, fused bias+relu.
// Cross layer and final N=1 head in fp32.

#define BM 128
#define BN 128
#define BK 32

typedef __bf16 bf16x8 __attribute__((ext_vector_type(8)));
typedef float  f32x4  __attribute__((ext_vector_type(4)));
typedef unsigned short u16x4 __attribute__((ext_vector_type(4)));
typedef float  f32x4v __attribute__((ext_vector_type(4)));

__device__ __forceinline__ unsigned short f2bf(float f) {
    unsigned int u = __builtin_bit_cast(unsigned int, f);
    u += 0x7fffu + ((u >> 16) & 1u);          // round-to-nearest-even
    return (unsigned short)(u >> 16);
}
__device__ __forceinline__ float bf2f(unsigned short h) {
    unsigned int u = ((unsigned int)h) << 16;
    return __builtin_bit_cast(float, u);
}

__device__ __forceinline__ void async16(const void* g, void* l) {
    __builtin_amdgcn_global_load_lds(
        (const __attribute__((address_space(1))) unsigned int*)g,
        (__attribute__((address_space(3))) unsigned int*)l,
        16, 0, 0);
}

// ---------------------------------------------------------------------------
// GEMM: C[M,N] = relu(A[M,K] * B[N,K]^T + bias[N]), all bf16 in, bf16 out,
// fp32 accumulate. M%128==0, N%128==0, K%32==0.
// ---------------------------------------------------------------------------
__global__ __launch_bounds__(256, 2)
void gemm_bt_bias_relu(const unsigned short* __restrict__ A,
                       const unsigned short* __restrict__ B,
                       const float* __restrict__ bias,
                       unsigned short* __restrict__ C,
                       int M, int N, int K)
{
    __shared__ __align__(16) unsigned short As[BM * BK];
    __shared__ __align__(16) unsigned short Bs[BN * BK];

    const int tid  = threadIdx.x;
    const int lane = tid & 63;
    const int wave = tid >> 6;
    const int quad = lane >> 4;
    const int l16  = lane & 15;

    const int bm = blockIdx.x * BM;
    const int bn = blockIdx.y * BN;
    const int wm = (wave & 1) * 64;   // wave's 64x64 patch
    const int wn = (wave >> 1) * 64;

    // staging: 256 threads x 16B = 4KB per issue; tile is 8KB -> 2 issues each
    const int lrow = tid >> 2;            // 4 threads per 32-elem row
    const int lcol = (tid & 3) * 8;

    const unsigned short* ga  = A + (size_t)(bm + lrow) * K + lcol;
    const unsigned short* ga2 = ga + (size_t)64 * K;
    const unsigned short* gb  = B + (size_t)(bn + lrow) * K + lcol;
    const unsigned short* gb2 = gb + (size_t)64 * K;

    unsigned short* lA  = As + tid * 8;   // byte off = wave*1024 + lane*16 (uniform+lane*16)
    unsigned short* lA2 = lA + 2048;
    unsigned short* lB  = Bs + tid * 8;
    unsigned short* lB2 = lB + 2048;

    const unsigned short* As_w = As + (wm + l16) * BK + quad * 8;
    const unsigned short* Bs_w = Bs + (wn + l16) * BK + quad * 8;

    f32x4 acc[4][4] = {};

    for (int k0 = 0; k0 < K; k0 += BK) {
        async16(ga  + k0, lA);
        async16(ga2 + k0, lA2);
        async16(gb  + k0, lB);
        async16(gb2 + k0, lB2);
        __syncthreads();

        bf16x8 af[4], bfr[4];
#pragma unroll
        for (int i = 0; i < 4; ++i) af[i]  = *(const bf16x8*)(As_w + i * 16 * BK);
#pragma unroll
        for (int j = 0; j < 4; ++j) bfr[j] = *(const bf16x8*)(Bs_w + j * 16 * BK);
#pragma unroll
        for (int i = 0; i < 4; ++i)
#pragma unroll
            for (int j = 0; j < 4; ++j)
                acc[i][j] = __builtin_amdgcn_mfma_f32_16x16x32_bf16(
                    af[i], bfr[j], acc[i][j], 0, 0, 0);
        __syncthreads();
    }

    float bv[4];
#pragma unroll
    for (int j = 0; j < 4; ++j) bv[j] = bias[bn + wn + j * 16 + l16];

#pragma unroll
    for (int i = 0; i < 4; ++i) {
        const int row0 = bm + wm + i * 16 + quad * 4;
#pragma unroll
        for (int j = 0; j < 4; ++j) {
            const int col = bn + wn + j * 16 + l16;
#pragma unroll
            for (int r = 0; r < 4; ++r) {
                float v = acc[i][j][r] + bv[j];
                v = fmaxf(v, 0.0f);
                C[(size_t)(row0 + r) * N + col] = f2bf(v);
            }
        }
    }
}

// ---------------------------------------------------------------------------
// Cross layer: per row, s = dot(x_row, cross_w); h0 = x*s + cross_b + x (bf16)
// One wave per row; 4 rows per 256-thread block.
// ---------------------------------------------------------------------------
__global__ __launch_bounds__(256)
void cross_kernel(const float* __restrict__ x, const float* __restrict__ cw,
                  const float* __restrict__ cb, unsigned short* __restrict__ h0)
{
    const int row  = blockIdx.x * 4 + (threadIdx.x >> 6);
    const int lane = threadIdx.x & 63;
    const float* xr = x + (size_t)row * 512;
    float xv[8];
    float s = 0.f;
#pragma unroll
    for (int i = 0; i < 8; ++i) {
        const int c = lane + i * 64;
        xv[i] = xr[c];
        s += xv[i] * cw[c];
    }
#pragma unroll
    for (int off = 32; off > 0; off >>= 1) s += __shfl_down(s, off, 64);
    s = __shfl(s, 0, 64);
    unsigned short* hr = h0 + (size_t)row * 512;
#pragma unroll
    for (int i = 0; i < 8; ++i) {
        const int c = lane + i * 64;
        hr[c] = f2bf(xv[i] * s + cb[c] + xv[i]);
    }
}

// ---------------------------------------------------------------------------
// Final head: out[m] = dot(h4[m,:512], Wo) + bo   (fp32)
// ---------------------------------------------------------------------------
__global__ __launch_bounds__(256)
void final_dot(const unsigned short* __restrict__ h4, const float* __restrict__ Wo,
               const float* __restrict__ bo, float* __restrict__ out)
{
    const int row  = blockIdx.x * 4 + (threadIdx.x >> 6);
    const int lane = threadIdx.x & 63;
    const unsigned short* hr = h4 + (size_t)row * 512;
    float s = 0.f;
#pragma unroll
    for (int i = 0; i < 8; ++i) {
        const int c = lane + i * 64;
        s += bf2f(hr[c]) * Wo[c];
    }
#pragma unroll
    for (int off = 32; off > 0; off >>= 1) s += __shfl_down(s, off, 64);
    if (lane == 0) out[row] = s + bo[0];
}

// ---------------------------------------------------------------------------
// fp32 -> bf16 conversion of W1..W4 in one grid-stride-free launch.
// vec4 segment sizes: W1 262144, W2 1048576, W3 524288, W4 131072 (cum 1966080)
// ---------------------------------------------------------------------------
__global__ __launch_bounds__(256)
void convert_weights(const float* __restrict__ s1, const float* __restrict__ s2,
                     const float* __restrict__ s3, const float* __restrict__ s4,
                     unsigned short* __restrict__ d1, unsigned short* __restrict__ d2,
                     unsigned short* __restrict__ d3, unsigned short* __restrict__ d4)
{
    long t = (long)blockIdx.x * 256 + threadIdx.x;
    const float* s; unsigned short* d; long off;
    if (t < 262144L)       { s = s1; d = d1; off = t; }
    else if (t < 1310720L) { s = s2; d = d2; off = t - 262144L; }
    else if (t < 1835008L) { s = s3; d = d3; off = t - 1310720L; }
    else                   { s = s4; d = d4; off = t - 1835008L; }
    f32x4 f = *(const f32x4*)(s + off * 4);
    u16x4 o;
#pragma unroll
    for (int i = 0; i < 4; ++i) o[i] = f2bf(f[i]);
    *(u16x4*)(d + off * 4) = o;
}

// ---------------------------------------------------------------------------
extern "C" void kernel_launch(void* const* d_in, const int* in_sizes, int n_in,
                              void* d_out, int out_size, void* d_ws, size_t ws_size,
                              hipStream_t stream)
{
    const float* x  = (const float*)d_in[0];
    const float* cw = (const float*)d_in[1];
    const float* cb = (const float*)d_in[2];
    const float* W1 = (const float*)d_in[3];  const float* b1 = (const float*)d_in[4];
    const float* W2 = (const float*)d_in[5];  const float* b2 = (const float*)d_in[6];
    const float* W3 = (const float*)d_in[7];  const float* b3 = (const float*)d_in[8];
    const float* W4 = (const float*)d_in[9];  const float* b4 = (const float*)d_in[10];
    const float* Wo = (const float*)d_in[11]; const float* bo = (const float*)d_in[12];
    float* out = (float*)d_out;

    // workspace carve (needs ~143 MB)
    char* p = (char*)d_ws;
    unsigned short* wb1 = (unsigned short*)p; p += (size_t)2048 * 512  * 2;
    unsigned short* wb2 = (unsigned short*)p; p += (size_t)2048 * 2048 * 2;
    unsigned short* wb3 = (unsigned short*)p; p += (size_t)1024 * 2048 * 2;
    unsigned short* wb4 = (unsigned short*)p; p += (size_t)512  * 1024 * 2;
    unsigned short* actA = (unsigned short*)p; p += (size_t)16384 * 2048 * 2; // h0,h2,h4
    unsigned short* actB = (unsigned short*)p;                                // h1,h3

    convert_weights<<<7680, 256, 0, stream>>>(W1, W2, W3, W4, wb1, wb2, wb3, wb4);
    cross_kernel<<<4096, 256, 0, stream>>>(x, cw, cb, actA);

    // h1 = relu(h0 @ W1^T + b1)   [16384,2048], K=512
    gemm_bt_bias_relu<<<dim3(128, 16), 256, 0, stream>>>(actA, wb1, b1, actB, 16384, 2048, 512);
    // h2 = relu(h1 @ W2^T + b2)   [16384,2048], K=2048
    gemm_bt_bias_relu<<<dim3(128, 16), 256, 0, stream>>>(actB, wb2, b2, actA, 16384, 2048, 2048);
    // h3 = relu(h2 @ W3^T + b3)   [16384,1024], K=2048
    gemm_bt_bias_relu<<<dim3(128, 8), 256, 0, stream>>>(actA, wb3, b3, actB, 16384, 1024, 2048);
    // h4 = relu(h3 @ W4^T + b4)   [16384,512], K=1024
    gemm_bt_bias_relu<<<dim3(128, 4), 256, 0, stream>>>(actB, wb4, b4, actA, 16384, 512, 1024);
    // out = h4 @ Wo^T + bo        [16384,1]
    final_dot<<<4096, 256, 0, stream>>>(actA, Wo, bo, out);
}

// Round 2
// 380.782 us; speedup vs baseline: 1.0948x; 1.0948x over previous
//
#include <hip/hip_runtime.h>

// Simple_Cross2: x[16384,512] -> cross -> 2048 -> 2048 -> 1024 -> 512 -> 1
// bf16 MFMA (16x16x32) GEMMs, fp32 accumulate, fused bias+relu.
// R2: BK 32->64 (half the barrier drains/FLOP, LDS 32KB keeps 4 blocks/CU)
//     + XOR-swizzled LDS layout (chunk ^= row&7) applied on the GLOBAL side of
//     global_load_lds so staging stays wave-uniform-base; kills the 8/16-way
//     ds_read_b128 bank conflicts (1.678e7 conflict-cycles in R1).

#define BM 128
#define BN 128
#define BK 64

typedef __bf16 bf16x8 __attribute__((ext_vector_type(8)));
typedef float  f32x4  __attribute__((ext_vector_type(4)));
typedef unsigned short u16x4 __attribute__((ext_vector_type(4)));

__device__ __forceinline__ unsigned short f2bf(float f) {
    unsigned int u = __builtin_bit_cast(unsigned int, f);
    u += 0x7fffu + ((u >> 16) & 1u);          // round-to-nearest-even
    return (unsigned short)(u >> 16);
}
__device__ __forceinline__ float bf2f(unsigned short h) {
    unsigned int u = ((unsigned int)h) << 16;
    return __builtin_bit_cast(float, u);
}

__device__ __forceinline__ void async16(const void* g, void* l) {
    __builtin_amdgcn_global_load_lds(
        (const __attribute__((address_space(1))) unsigned int*)g,
        (__attribute__((address_space(3))) unsigned int*)l,
        16, 0, 0);
}

// ---------------------------------------------------------------------------
// C[M,N] = relu(A[M,K] * B[N,K]^T + bias[N]); bf16 in/out, fp32 acc.
// M%128==0, N%128==0, K%64==0.
// LDS layout: elem(row,c) at row*64 + (((c>>3) ^ (row&7))*8 + (c&7))
// ---------------------------------------------------------------------------
__global__ __launch_bounds__(256, 2)
void gemm_bt_bias_relu(const unsigned short* __restrict__ A,
                       const unsigned short* __restrict__ B,
                       const float* __restrict__ bias,
                       unsigned short* __restrict__ C,
                       int M, int N, int K)
{
    __shared__ __align__(16) unsigned short As[BM * BK];   // 16 KB
    __shared__ __align__(16) unsigned short Bs[BN * BK];   // 16 KB

    const int tid  = threadIdx.x;
    const int lane = tid & 63;
    const int wave = tid >> 6;
    const int quad = lane >> 4;
    const int l16  = lane & 15;

    const int bm = blockIdx.x * BM;
    const int bn = blockIdx.y * BN;
    const int wm = (wave & 1) * 64;   // wave's 64x64 patch
    const int wn = (wave >> 1) * 64;

    // staging: thread t -> row (t>>3)+32i, swizzled col chunk (t&7)^(row&7).
    // (row&7) is i-invariant since rows step by 32 -> gcol constant per thread.
    const int lrow = tid >> 3;
    const int gcol = ((tid & 7) ^ (lrow & 7)) * 8;

    const unsigned short* gaBase = A + (size_t)(bm + lrow) * K + gcol;
    const unsigned short* gbBase = B + (size_t)(bn + lrow) * K + gcol;

    unsigned short* lA = As + tid * 8;    // LDS dest: uniform base + lane*16B
    unsigned short* lB = Bs + tid * 8;

    // fragment read bases: row = (wm|wn) + sub*16 + l16; xor factor = l16&7
    const int xa = l16 & 7;
    const unsigned short* As_w = As + (wm + l16) * BK;
    const unsigned short* Bs_w = Bs + (wn + l16) * BK;
    const int c0 = (quad ^ xa) * 8;          // kk=0  -> chunks 0..3
    const int c1 = ((quad ^ 4) ^ xa) * 8;    // kk=32 -> chunks 4..7

    f32x4 acc[4][4] = {};

    for (int k0 = 0; k0 < K; k0 += BK) {
#pragma unroll
        for (int i = 0; i < 4; ++i) {
            async16(gaBase + (size_t)(i * 32) * K + k0, lA + i * 2048);
            async16(gbBase + (size_t)(i * 32) * K + k0, lB + i * 2048);
        }
        __syncthreads();

#pragma unroll
        for (int kk = 0; kk < 2; ++kk) {
            const int cs = kk ? c1 : c0;
            bf16x8 af[4], bfr[4];
#pragma unroll
            for (int i = 0; i < 4; ++i) af[i]  = *(const bf16x8*)(As_w + i * 16 * BK + cs);
#pragma unroll
            for (int j = 0; j < 4; ++j) bfr[j] = *(const bf16x8*)(Bs_w + j * 16 * BK + cs);
#pragma unroll
            for (int i = 0; i < 4; ++i)
#pragma unroll
                for (int j = 0; j < 4; ++j)
                    acc[i][j] = __builtin_amdgcn_mfma_f32_16x16x32_bf16(
                        af[i], bfr[j], acc[i][j], 0, 0, 0);
        }
        __syncthreads();
    }

    float bv[4];
#pragma unroll
    for (int j = 0; j < 4; ++j) bv[j] = bias[bn + wn + j * 16 + l16];

#pragma unroll
    for (int i = 0; i < 4; ++i) {
        const int row0 = bm + wm + i * 16 + quad * 4;
#pragma unroll
        for (int j = 0; j < 4; ++j) {
            const int col = bn + wn + j * 16 + l16;
#pragma unroll
            for (int r = 0; r < 4; ++r) {
                float v = acc[i][j][r] + bv[j];
                v = fmaxf(v, 0.0f);
                C[(size_t)(row0 + r) * N + col] = f2bf(v);
            }
        }
    }
}

// ---------------------------------------------------------------------------
// Cross layer: s = dot(x_row, cross_w); h0 = x*s + cross_b + x  (bf16 out)
// ---------------------------------------------------------------------------
__global__ __launch_bounds__(256)
void cross_kernel(const float* __restrict__ x, const float* __restrict__ cw,
                  const float* __restrict__ cb, unsigned short* __restrict__ h0)
{
    const int row  = blockIdx.x * 4 + (threadIdx.x >> 6);
    const int lane = threadIdx.x & 63;
    const float* xr = x + (size_t)row * 512;
    float xv[8];
    float s = 0.f;
#pragma unroll
    for (int i = 0; i < 8; ++i) {
        const int c = lane + i * 64;
        xv[i] = xr[c];
        s += xv[i] * cw[c];
    }
#pragma unroll
    for (int off = 32; off > 0; off >>= 1) s += __shfl_down(s, off, 64);
    s = __shfl(s, 0, 64);
    unsigned short* hr = h0 + (size_t)row * 512;
#pragma unroll
    for (int i = 0; i < 8; ++i) {
        const int c = lane + i * 64;
        hr[c] = f2bf(xv[i] * s + cb[c] + xv[i]);
    }
}

// ---------------------------------------------------------------------------
// Final head: out[m] = dot(h4[m,:512], Wo) + bo   (fp32)
// ---------------------------------------------------------------------------
__global__ __launch_bounds__(256)
void final_dot(const unsigned short* __restrict__ h4, const float* __restrict__ Wo,
               const float* __restrict__ bo, float* __restrict__ out)
{
    const int row  = blockIdx.x * 4 + (threadIdx.x >> 6);
    const int lane = threadIdx.x & 63;
    const unsigned short* hr = h4 + (size_t)row * 512;
    float s = 0.f;
#pragma unroll
    for (int i = 0; i < 8; ++i) {
        const int c = lane + i * 64;
        s += bf2f(hr[c]) * Wo[c];
    }
#pragma unroll
    for (int off = 32; off > 0; off >>= 1) s += __shfl_down(s, off, 64);
    if (lane == 0) out[row] = s + bo[0];
}

// ---------------------------------------------------------------------------
// fp32 -> bf16 conversion of W1..W4.
// vec4 segments: W1 262144, W2 1048576, W3 524288, W4 131072 (cum 1966080)
// ---------------------------------------------------------------------------
__global__ __launch_bounds__(256)
void convert_weights(const float* __restrict__ s1, const float* __restrict__ s2,
                     const float* __restrict__ s3, const float* __restrict__ s4,
                     unsigned short* __restrict__ d1, unsigned short* __restrict__ d2,
                     unsigned short* __restrict__ d3, unsigned short* __restrict__ d4)
{
    long t = (long)blockIdx.x * 256 + threadIdx.x;
    const float* s; unsigned short* d; long off;
    if (t < 262144L)       { s = s1; d = d1; off = t; }
    else if (t < 1310720L) { s = s2; d = d2; off = t - 262144L; }
    else if (t < 1835008L) { s = s3; d = d3; off = t - 1310720L; }
    else                   { s = s4; d = d4; off = t - 1835008L; }
    f32x4 f = *(const f32x4*)(s + off * 4);
    u16x4 o;
#pragma unroll
    for (int i = 0; i < 4; ++i) o[i] = f2bf(f[i]);
    *(u16x4*)(d + off * 4) = o;
}

// ---------------------------------------------------------------------------
extern "C" void kernel_launch(void* const* d_in, const int* in_sizes, int n_in,
                              void* d_out, int out_size, void* d_ws, size_t ws_size,
                              hipStream_t stream)
{
    const float* x  = (const float*)d_in[0];
    const float* cw = (const float*)d_in[1];
    const float* cb = (const float*)d_in[2];
    const float* W1 = (const float*)d_in[3];  const float* b1 = (const float*)d_in[4];
    const float* W2 = (const float*)d_in[5];  const float* b2 = (const float*)d_in[6];
    const float* W3 = (const float*)d_in[7];  const float* b3 = (const float*)d_in[8];
    const float* W4 = (const float*)d_in[9];  const float* b4 = (const float*)d_in[10];
    const float* Wo = (const float*)d_in[11]; const float* bo = (const float*)d_in[12];
    float* out = (float*)d_out;

    // workspace carve (~143 MB)
    char* p = (char*)d_ws;
    unsigned short* wb1 = (unsigned short*)p; p += (size_t)2048 * 512  * 2;
    unsigned short* wb2 = (unsigned short*)p; p += (size_t)2048 * 2048 * 2;
    unsigned short* wb3 = (unsigned short*)p; p += (size_t)1024 * 2048 * 2;
    unsigned short* wb4 = (unsigned short*)p; p += (size_t)512  * 1024 * 2;
    unsigned short* actA = (unsigned short*)p; p += (size_t)16384 * 2048 * 2; // h0,h2,h4
    unsigned short* actB = (unsigned short*)p;                                // h1,h3

    convert_weights<<<7680, 256, 0, stream>>>(W1, W2, W3, W4, wb1, wb2, wb3, wb4);
    cross_kernel<<<4096, 256, 0, stream>>>(x, cw, cb, actA);

    // h1 = relu(h0 @ W1^T + b1)   [16384,2048], K=512
    gemm_bt_bias_relu<<<dim3(128, 16), 256, 0, stream>>>(actA, wb1, b1, actB, 16384, 2048, 512);
    // h2 = relu(h1 @ W2^T + b2)   [16384,2048], K=2048
    gemm_bt_bias_relu<<<dim3(128, 16), 256, 0, stream>>>(actB, wb2, b2, actA, 16384, 2048, 2048);
    // h3 = relu(h2 @ W3^T + b3)   [16384,1024], K=2048
    gemm_bt_bias_relu<<<dim3(128, 8), 256, 0, stream>>>(actA, wb3, b3, actB, 16384, 1024, 2048);
    // h4 = relu(h3 @ W4^T + b4)   [16384,512], K=1024
    gemm_bt_bias_relu<<<dim3(128, 4), 256, 0, stream>>>(actB, wb4, b4, actA, 16384, 512, 1024);
    // out = h4 @ Wo^T + bo        [16384,1]
    final_dot<<<4096, 256, 0, stream>>>(actA, Wo, bo, out);
}

// Round 3
// 355.584 us; speedup vs baseline: 1.1724x; 1.0709x over previous
//
#include <hip/hip_runtime.h>

// Simple_Cross2: x[16384,512] -> cross -> 2048 -> 2048 -> 1024 -> 512 -> 1
// bf16 MFMA (16x16x32) GEMMs, fp32 accumulate, fused bias+relu.
// R2: BK=64 + XOR swizzle -> 0 bank conflicts, MfmaUtil 47%.
// R3: LDS-BW-bound analysis -> asymmetric 64x128 wave tile (4x8 acc),
//     block 128x256. LDS fragment bytes/FLOP drop 25% (0.031->0.023).
//     Occupancy drops to ~2 blocks/CU (128 AGPR acc) -- accepted risk.

#define BM 128
#define BN 256
#define BK 64

typedef __bf16 bf16x8 __attribute__((ext_vector_type(8)));
typedef float  f32x4  __attribute__((ext_vector_type(4)));
typedef unsigned short u16x4 __attribute__((ext_vector_type(4)));

__device__ __forceinline__ unsigned short f2bf(float f) {
    unsigned int u = __builtin_bit_cast(unsigned int, f);
    u += 0x7fffu + ((u >> 16) & 1u);          // round-to-nearest-even
    return (unsigned short)(u >> 16);
}
__device__ __forceinline__ float bf2f(unsigned short h) {
    unsigned int u = ((unsigned int)h) << 16;
    return __builtin_bit_cast(float, u);
}

__device__ __forceinline__ void async16(const void* g, void* l) {
    __builtin_amdgcn_global_load_lds(
        (const __attribute__((address_space(1))) unsigned int*)g,
        (__attribute__((address_space(3))) unsigned int*)l,
        16, 0, 0);
}

// ---------------------------------------------------------------------------
// C[M,N] = relu(A[M,K] * B[N,K]^T + bias[N]); bf16 in/out, fp32 acc.
// M%128==0, N%256==0, K%64==0.
// LDS layout: elem(row,c) at row*64 + (((c>>3) ^ (row&7))*8 + (c&7))
// ---------------------------------------------------------------------------
__global__ __launch_bounds__(256, 2)
void gemm_bt_bias_relu(const unsigned short* __restrict__ A,
                       const unsigned short* __restrict__ B,
                       const float* __restrict__ bias,
                       unsigned short* __restrict__ C,
                       int M, int N, int K)
{
    __shared__ __align__(16) unsigned short As[BM * BK];   // 16 KB
    __shared__ __align__(16) unsigned short Bs[BN * BK];   // 32 KB

    const int tid  = threadIdx.x;
    const int lane = tid & 63;
    const int wave = tid >> 6;
    const int quad = lane >> 4;
    const int l16  = lane & 15;

    const int bm = blockIdx.x * BM;
    const int bn = blockIdx.y * BN;
    const int wm = (wave & 1) * 64;    // wave's 64x128 patch
    const int wn = (wave >> 1) * 128;

    // staging: thread t -> row (t>>3)+32i, swizzled col chunk (t&7)^(row&7).
    // (row&7) is i-invariant since rows step by 32 -> gcol constant per thread.
    const int lrow = tid >> 3;
    const int gcol = ((tid & 7) ^ (lrow & 7)) * 8;

    const unsigned short* gaBase = A + (size_t)(bm + lrow) * K + gcol;
    const unsigned short* gbBase = B + (size_t)(bn + lrow) * K + gcol;

    unsigned short* lA = As + tid * 8;    // LDS dest: uniform base + lane*16B
    unsigned short* lB = Bs + tid * 8;

    // fragment read bases: row = (wm|wn) + sub*16 + l16; xor factor = l16&7
    const int xa = l16 & 7;
    const unsigned short* As_w = As + (wm + l16) * BK;
    const unsigned short* Bs_w = Bs + (wn + l16) * BK;
    const int c0 = (quad ^ xa) * 8;          // kk=0  -> chunks 0..3
    const int c1 = ((quad ^ 4) ^ xa) * 8;    // kk=32 -> chunks 4..7

    f32x4 acc[4][8] = {};

    for (int k0 = 0; k0 < K; k0 += BK) {
#pragma unroll
        for (int i = 0; i < 4; ++i)
            async16(gaBase + (size_t)(i * 32) * K + k0, lA + i * 2048);
#pragma unroll
        for (int i = 0; i < 8; ++i)
            async16(gbBase + (size_t)(i * 32) * K + k0, lB + i * 2048);
        __syncthreads();

#pragma unroll
        for (int kk = 0; kk < 2; ++kk) {
            const int cs = kk ? c1 : c0;
            bf16x8 af[4], bfr[8];
#pragma unroll
            for (int i = 0; i < 4; ++i) af[i]  = *(const bf16x8*)(As_w + i * 16 * BK + cs);
#pragma unroll
            for (int j = 0; j < 8; ++j) bfr[j] = *(const bf16x8*)(Bs_w + j * 16 * BK + cs);
#pragma unroll
            for (int i = 0; i < 4; ++i)
#pragma unroll
                for (int j = 0; j < 8; ++j)
                    acc[i][j] = __builtin_amdgcn_mfma_f32_16x16x32_bf16(
                        af[i], bfr[j], acc[i][j], 0, 0, 0);
        }
        __syncthreads();
    }

    float bv[8];
#pragma unroll
    for (int j = 0; j < 8; ++j) bv[j] = bias[bn + wn + j * 16 + l16];

#pragma unroll
    for (int i = 0; i < 4; ++i) {
        const int row0 = bm + wm + i * 16 + quad * 4;
#pragma unroll
        for (int j = 0; j < 8; ++j) {
            const int col = bn + wn + j * 16 + l16;
#pragma unroll
            for (int r = 0; r < 4; ++r) {
                float v = acc[i][j][r] + bv[j];
                v = fmaxf(v, 0.0f);
                C[(size_t)(row0 + r) * N + col] = f2bf(v);
            }
        }
    }
}

// ---------------------------------------------------------------------------
// Cross layer: s = dot(x_row, cross_w); h0 = x*s + cross_b + x  (bf16 out)
// ---------------------------------------------------------------------------
__global__ __launch_bounds__(256)
void cross_kernel(const float* __restrict__ x, const float* __restrict__ cw,
                  const float* __restrict__ cb, unsigned short* __restrict__ h0)
{
    const int row  = blockIdx.x * 4 + (threadIdx.x >> 6);
    const int lane = threadIdx.x & 63;
    const float* xr = x + (size_t)row * 512;
    float xv[8];
    float s = 0.f;
#pragma unroll
    for (int i = 0; i < 8; ++i) {
        const int c = lane + i * 64;
        xv[i] = xr[c];
        s += xv[i] * cw[c];
    }
#pragma unroll
    for (int off = 32; off > 0; off >>= 1) s += __shfl_down(s, off, 64);
    s = __shfl(s, 0, 64);
    unsigned short* hr = h0 + (size_t)row * 512;
#pragma unroll
    for (int i = 0; i < 8; ++i) {
        const int c = lane + i * 64;
        hr[c] = f2bf(xv[i] * s + cb[c] + xv[i]);
    }
}

// ---------------------------------------------------------------------------
// Final head: out[m] = dot(h4[m,:512], Wo) + bo   (fp32)
// ---------------------------------------------------------------------------
__global__ __launch_bounds__(256)
void final_dot(const unsigned short* __restrict__ h4, const float* __restrict__ Wo,
               const float* __restrict__ bo, float* __restrict__ out)
{
    const int row  = blockIdx.x * 4 + (threadIdx.x >> 6);
    const int lane = threadIdx.x & 63;
    const unsigned short* hr = h4 + (size_t)row * 512;
    float s = 0.f;
#pragma unroll
    for (int i = 0; i < 8; ++i) {
        const int c = lane + i * 64;
        s += bf2f(hr[c]) * Wo[c];
    }
#pragma unroll
    for (int off = 32; off > 0; off >>= 1) s += __shfl_down(s, off, 64);
    if (lane == 0) out[row] = s + bo[0];
}

// ---------------------------------------------------------------------------
// fp32 -> bf16 conversion of W1..W4.
// vec4 segments: W1 262144, W2 1048576, W3 524288, W4 131072 (cum 1966080)
// ---------------------------------------------------------------------------
__global__ __launch_bounds__(256)
void convert_weights(const float* __restrict__ s1, const float* __restrict__ s2,
                     const float* __restrict__ s3, const float* __restrict__ s4,
                     unsigned short* __restrict__ d1, unsigned short* __restrict__ d2,
                     unsigned short* __restrict__ d3, unsigned short* __restrict__ d4)
{
    long t = (long)blockIdx.x * 256 + threadIdx.x;
    const float* s; unsigned short* d; long off;
    if (t < 262144L)       { s = s1; d = d1; off = t; }
    else if (t < 1310720L) { s = s2; d = d2; off = t - 262144L; }
    else if (t < 1835008L) { s = s3; d = d3; off = t - 1310720L; }
    else                   { s = s4; d = d4; off = t - 1835008L; }
    f32x4 f = *(const f32x4*)(s + off * 4);
    u16x4 o;
#pragma unroll
    for (int i = 0; i < 4; ++i) o[i] = f2bf(f[i]);
    *(u16x4*)(d + off * 4) = o;
}

// ---------------------------------------------------------------------------
extern "C" void kernel_launch(void* const* d_in, const int* in_sizes, int n_in,
                              void* d_out, int out_size, void* d_ws, size_t ws_size,
                              hipStream_t stream)
{
    const float* x  = (const float*)d_in[0];
    const float* cw = (const float*)d_in[1];
    const float* cb = (const float*)d_in[2];
    const float* W1 = (const float*)d_in[3];  const float* b1 = (const float*)d_in[4];
    const float* W2 = (const float*)d_in[5];  const float* b2 = (const float*)d_in[6];
    const float* W3 = (const float*)d_in[7];  const float* b3 = (const float*)d_in[8];
    const float* W4 = (const float*)d_in[9];  const float* b4 = (const float*)d_in[10];
    const float* Wo = (const float*)d_in[11]; const float* bo = (const float*)d_in[12];
    float* out = (float*)d_out;

    // workspace carve (~143 MB)
    char* p = (char*)d_ws;
    unsigned short* wb1 = (unsigned short*)p; p += (size_t)2048 * 512  * 2;
    unsigned short* wb2 = (unsigned short*)p; p += (size_t)2048 * 2048 * 2;
    unsigned short* wb3 = (unsigned short*)p; p += (size_t)1024 * 2048 * 2;
    unsigned short* wb4 = (unsigned short*)p; p += (size_t)512  * 1024 * 2;
    unsigned short* actA = (unsigned short*)p; p += (size_t)16384 * 2048 * 2; // h0,h2,h4
    unsigned short* actB = (unsigned short*)p;                                // h1,h3

    convert_weights<<<7680, 256, 0, stream>>>(W1, W2, W3, W4, wb1, wb2, wb3, wb4);
    cross_kernel<<<4096, 256, 0, stream>>>(x, cw, cb, actA);

    // h1 = relu(h0 @ W1^T + b1)   [16384,2048], K=512
    gemm_bt_bias_relu<<<dim3(128, 8), 256, 0, stream>>>(actA, wb1, b1, actB, 16384, 2048, 512);
    // h2 = relu(h1 @ W2^T + b2)   [16384,2048], K=2048
    gemm_bt_bias_relu<<<dim3(128, 8), 256, 0, stream>>>(actB, wb2, b2, actA, 16384, 2048, 2048);
    // h3 = relu(h2 @ W3^T + b3)   [16384,1024], K=2048
    gemm_bt_bias_relu<<<dim3(128, 4), 256, 0, stream>>>(actA, wb3, b3, actB, 16384, 1024, 2048);
    // h4 = relu(h3 @ W4^T + b4)   [16384,512], K=1024
    gemm_bt_bias_relu<<<dim3(128, 2), 256, 0, stream>>>(actB, wb4, b4, actA, 16384, 512, 1024);
    // out = h4 @ Wo^T + bo        [16384,1]
    final_dot<<<4096, 256, 0, stream>>>(actA, Wo, bo, out);
}